// Round 8
// baseline (304.240 us; speedup 1.0000x reference)
//
#include <hip/hip_runtime.h>

// FSUConv2d stochastic-computing conv.
// N=8, C=32, H=W=16, OC=64, K=3, PAD=1, RLEN=256, CKK=288, B=N*H*W=2048.
//
// out[n,o,h,w] = sum_k [ x_k ? (w_bin[o,k] > rev8(i1)) : !(w_bin[o,k] > rev8(i0)) ]
//               + (b_bin[o] > rev8(brdx[o]))
//
// ROUND-8: r7 structure (nt loads -> no L3 allocation throttle; integer
// compare wkey > brev(i); wave-wide ballot+popcll; LDS unfold) with the
// per-wave stream batch doubled: 4 rows/wave, 4 blocks/patch.
//   r6 proved the L3-allocation bypass (109 -> <87us); r7's 2-rows/wave
//   cut overhead further (bench -12us => kernel ~74us, 4.1 TB/s). The
//   harness fill kernels sustain 6.9 TB/s at 9.5% occupancy => streaming
//   rate is set by per-wave MLP x duty cycle. 4 rows/wave = 24 nt dwordx4
//   (~16 KB) in flight per wave, issued straight-line before any consume
//   (sched_barrier(0) fence), unfold redundancy x8 -> x4, grid halved.
// All identities verified absmax 0 in rounds 0-7.

#define CH   32
#define HH   16
#define WW   16
#define OCN  64
#define CKK  288
#define LL   256     // H*W
#define BB   2048    // N*H*W

__device__ __forceinline__ float sobol_val(int idx) {
    // idx guaranteed in [0, 256) by setup (randint(0, RLEN))
    return (float)(__brev((unsigned)idx) >> 24);
}

// (w > rev8(i)) as unsigned compare: brev(i) = rev8<<24 for i in [0,256);
// wkey = w<<24 saturated (w integral in [0,256]; 256 -> always true).
__device__ __forceinline__ unsigned wkeyf(float wv) {
    unsigned wi = (unsigned)wv;
    return (wi >= 256u) ? 0xFFFFFFFFu : (wi << 24);
}

// 16B non-temporal load: global_load_dwordx4 ... nt (no L2/L3 allocation)
__device__ __forceinline__ int4 ntload(const int4* p) {
    typedef __attribute__((ext_vector_type(4))) int i4;
    i4 v = __builtin_nontemporal_load((const i4*)p);
    return make_int4(v.x, v.y, v.z, v.w);
}

// bit = x ? (k > brev(i1)) : !(k > brev(i0)), as a 64-bit wave mask
__device__ __forceinline__ unsigned long long chunkm(unsigned k, int a1, int a0,
                                                     unsigned long long xm) {
    unsigned long long m1 = __ballot(k > __brev((unsigned)a1));
    unsigned long long m0 = __ballot(k > __brev((unsigned)a0));
    return (xm & m1) | (~xm & ~m0);
}

struct RowRegs {
    int4   a, c;     // wrdx1/wrdx0 main: k = lane*4 .. +3
    int4   at, ct;   // tail (broadcast 8x): k = 256+(lane&7)*4 .. +3
    float4 wv, wt;   // weights, same k
};

__global__ __launch_bounds__(256) void fsuconv_kernel(
    const float* __restrict__ x,       // [8,32,16,16] bits
    const float* __restrict__ w_bin,   // [64,288]
    const float* __restrict__ b_bin,   // [64]
    const int*   __restrict__ wrdx1,   // [2048,64,288]
    const int*   __restrict__ wrdx0,   // [2048,64,288]
    const int*   __restrict__ brdx,    // [64]
    float*       __restrict__ out)     // [8,64,16,16]
{
    __shared__ __align__(16) float ib1[CKK];

    const int blk = blockIdx.x;        // = b*4 + og
    const int b   = blk >> 2;          // patch index in [0, 2048)
    const int og  = blk & 3;           // o-group of 16: o = og*16 + wave*4 + r
    const int n   = b >> 8;
    const int l   = b & 255;
    const int h   = l >> 4;
    const int w0  = l & 15;

    // Phase 1: unfold x-row for this patch into LDS (288 bits as floats).
    for (int k = threadIdx.x; k < CKK; k += 256) {
        int c  = k / 9;
        int r  = k - c * 9;
        int kh = r / 3;
        int kw = r - kh * 3;
        int ih = h + kh - 1;
        int iw = w0 + kw - 1;
        float v = 0.f;
        if ((unsigned)ih < 16u && (unsigned)iw < 16u)
            v = x[((n * CH + c) * HH + ih) * WW + iw];
        ib1[k] = v;
    }
    __syncthreads();

    const int wave = threadIdx.x >> 6;
    const int lane = threadIdx.x & 63;
    const int tl   = 64 + (lane & 7);   // tail chunk: broadcast 8x across wave

    // Fold x to 8 wave-wide ballot masks (SGPR-resident; tail bits 0..7 valid)
    float4 xv = ((const float4*)ib1)[lane];
    float4 xt = ((const float4*)ib1)[tl];
    const unsigned long long x0 = __ballot(xv.x != 0.f);
    const unsigned long long x1 = __ballot(xv.y != 0.f);
    const unsigned long long x2 = __ballot(xv.z != 0.f);
    const unsigned long long x3 = __ballot(xv.w != 0.f);
    const unsigned long long y0 = __ballot(xt.x != 0.f);
    const unsigned long long y1 = __ballot(xt.y != 0.f);
    const unsigned long long y2 = __ballot(xt.z != 0.f);
    const unsigned long long y3 = __ballot(xt.w != 0.f);

    // Four rows per wave: o = o0 .. o0+3.
    const int o0 = og * 16 + wave * 4;
    const size_t base = ((size_t)b * OCN + o0) * CKK;

    RowRegs R[4];
    // Issue ALL vmem straight-line (24 independent nt dwordx4 + 8 cached
    // weight loads) before any consume; fence stops the scheduler from
    // sinking later loads below earlier computes (the round-1 failure mode).
    #pragma unroll
    for (int r = 0; r < 4; ++r) {
        const int4*   r1 = (const int4*)(wrdx1 + base + (size_t)r * CKK);
        const int4*   r0 = (const int4*)(wrdx0 + base + (size_t)r * CKK);
        const float4* wr = (const float4*)(w_bin + (size_t)(o0 + r) * CKK);
        R[r].a  = ntload(&r1[lane]);
        R[r].c  = ntload(&r0[lane]);
        R[r].at = ntload(&r1[tl]);
        R[r].ct = ntload(&r0[tl]);
        R[r].wv = wr[lane];
        R[r].wt = wr[tl];
    }
    __builtin_amdgcn_sched_barrier(0);

    #pragma unroll
    for (int r = 0; r < 4; ++r) {
        unsigned cnt = 0;
        cnt += __popcll(chunkm(wkeyf(R[r].wv.x), R[r].a.x,  R[r].c.x,  x0));
        cnt += __popcll(chunkm(wkeyf(R[r].wv.y), R[r].a.y,  R[r].c.y,  x1));
        cnt += __popcll(chunkm(wkeyf(R[r].wv.z), R[r].a.z,  R[r].c.z,  x2));
        cnt += __popcll(chunkm(wkeyf(R[r].wv.w), R[r].a.w,  R[r].c.w,  x3));
        // tail: broadcast 8x across the wave -> bits 0..7 only
        cnt += __popcll(chunkm(wkeyf(R[r].wt.x), R[r].at.x, R[r].ct.x, y0) & 0xFFull);
        cnt += __popcll(chunkm(wkeyf(R[r].wt.y), R[r].at.y, R[r].ct.y, y1) & 0xFFull);
        cnt += __popcll(chunkm(wkeyf(R[r].wt.z), R[r].at.z, R[r].ct.z, y2) & 0xFFull);
        cnt += __popcll(chunkm(wkeyf(R[r].wt.w), R[r].at.w, R[r].ct.w, y3) & 0xFFull);
        if (lane == 0) {
            const int o = o0 + r;
            float bb = (b_bin[o] > sobol_val(brdx[o])) ? 1.f : 0.f;
            out[((size_t)n * OCN + o) * LL + l] = (float)cnt + bb;
        }
    }
}

extern "C" void kernel_launch(void* const* d_in, const int* in_sizes, int n_in,
                              void* d_out, int out_size, void* d_ws, size_t ws_size,
                              hipStream_t stream) {
    const float* x     = (const float*)d_in[0];
    const float* w_bin = (const float*)d_in[1];
    const float* b_bin = (const float*)d_in[2];
    // d_in[3] = rng — replaced by closed-form bit-reversal (see sobol_val)
    const int*   wrdx1 = (const int*)d_in[4];
    const int*   wrdx0 = (const int*)d_in[5];
    const int*   brdx  = (const int*)d_in[6];
    float*       out   = (float*)d_out;

    // one block per (patch b, o-group of 16); wave w handles o = og*16 + w*4 + r
    dim3 grid(BB * 4);
    dim3 block(256);
    fsuconv_kernel<<<grid, block, 0, stream>>>(x, w_bin, b_bin, wrdx1, wrdx0, brdx, out);
}